// Round 8
// baseline (10646.120 us; speedup 1.0000x reference)
//
#include <hip/hip_runtime.h>
#include <math.h>

// ---------------- constants ----------------
#define EMB    768
#define NH     12
#define HDIM   64
#define SEQ    1024
#define NLAYER 6
#define NVOCAB 50257
#define NTOK   4096          // B*T = 4*1024

static constexpr float ATT_SCALE = 0.03608439182435161f;  // 768^-0.5 (model scales by EMBED_DIM)

typedef unsigned short ushort_t;
typedef __attribute__((ext_vector_type(8))) short short8v;   // 8 bf16 in 4 VGPRs
typedef __attribute__((ext_vector_type(4))) float float4v;   // MFMA accumulator

__device__ __forceinline__ ushort_t f2bf(float f) {
    union { float f; unsigned u; } v; v.f = f;
    unsigned r = v.u + 0x7FFFu + ((v.u >> 16) & 1u);   // round-to-nearest-even
    return (ushort_t)(r >> 16);
}

// ---------------- embedding ----------------
__global__ __launch_bounds__(256) void embed_kernel(
    const int* __restrict__ idx, const float* __restrict__ tok,
    const float* __restrict__ pos, float* __restrict__ x)
{
    int i = blockIdx.x * 256 + threadIdx.x;           // over NTOK * EMB/4
    if (i >= NTOK * (EMB / 4)) return;
    int row = i / (EMB / 4);
    int c   = i % (EMB / 4);
    int token = idx[row];
    float4 tv = ((const float4*)tok)[(size_t)token * (EMB / 4) + c];
    float4 pv = ((const float4*)pos)[(size_t)(row & (SEQ - 1)) * (EMB / 4) + c];
    float4 o; o.x = tv.x + pv.x; o.y = tv.y + pv.y; o.z = tv.z + pv.z; o.w = tv.w + pv.w;
    ((float4*)x)[i] = o;
}

// ---------------- layernorm (one block per row) ----------------
__global__ __launch_bounds__(256) void ln_kernel(
    const float* __restrict__ x, const float* __restrict__ g,
    const float* __restrict__ b, float* __restrict__ out)
{
    int row = blockIdx.x;
    int tid = threadIdx.x;
    const float* xr = x + (size_t)row * EMB;
    float v[3];
    float s = 0.f, sq = 0.f;
#pragma unroll
    for (int j = 0; j < 3; ++j) {
        v[j] = xr[tid + j * 256];
        s += v[j];
        sq += v[j] * v[j];
    }
    __shared__ float rs[256], rq[256];
    rs[tid] = s; rq[tid] = sq;
    __syncthreads();
    for (int off = 128; off > 0; off >>= 1) {
        if (tid < off) { rs[tid] += rs[tid + off]; rq[tid] += rq[tid + off]; }
        __syncthreads();
    }
    float mean = rs[0] * (1.f / EMB);
    float var  = rq[0] * (1.f / EMB) - mean * mean;
    float rstd = rsqrtf(var + 1e-5f);
    float* orow = out + (size_t)row * EMB;
#pragma unroll
    for (int j = 0; j < 3; ++j) {
        int e = tid + j * 256;
        orow[e] = (v[j] - mean) * rstd * g[e] + b[e];
    }
}

// ---------------- GEMM: C(M,N) = A(M,K) @ B(K,N) [+bias][+res][relu] ----------------
// BHEAD: B is per-head Wq/Wk/Wv layout (H,E,HD): elem(k,n) = B[(n>>6)*E*HD + k*HD + (n&63)]
// CQKV:  C written in (b,h,t,d) layout for attention consumption
template<bool BHEAD, bool CQKV, bool BIAS, bool RES, bool RELU>
__global__ __launch_bounds__(256) void gemm_kernel(
    const float* __restrict__ A, const float* __restrict__ Bm,
    const float* __restrict__ bias, const float* __restrict__ res,
    float* __restrict__ C, int M, int N, int K)
{
    constexpr int BMT = 128, BNT = 128, BKT = 16;
    __shared__ float la[BKT][BMT];   // A^T tile: [k][m]
    __shared__ float lb[BKT][BNT];   // B tile:   [k][n]

    int tid = threadIdx.x;
    int m0 = blockIdx.x * BMT;       // x = m-tile (fast) -> B-panel reuse in L2
    int n0 = blockIdx.y * BNT;
    int tm = tid >> 4, tn = tid & 15;

    float acc[8][8];
#pragma unroll
    for (int i = 0; i < 8; ++i)
#pragma unroll
        for (int j = 0; j < 8; ++j) acc[i][j] = 0.f;

    int am = tid >> 2;                 // 0..63 (+64)
    int ak = (tid & 3) << 2;           // 0,4,8,12
    int bk = tid >> 5;                 // 0..7 (+8)
    int bn = (tid & 31) << 2;          // 0..124

    for (int k0 = 0; k0 < K; k0 += BKT) {
        // A tile load (coalesced float4 along K), store transposed
#pragma unroll
        for (int h = 0; h < 2; ++h) {
            int m = am + h * 64;
            float4 av = *(const float4*)&A[(size_t)(m0 + m) * K + k0 + ak];
            la[ak + 0][m] = av.x; la[ak + 1][m] = av.y;
            la[ak + 2][m] = av.z; la[ak + 3][m] = av.w;
        }
        // B tile load
#pragma unroll
        for (int h = 0; h < 2; ++h) {
            int kk = bk + h * 8;
            int n = n0 + bn;
            float4 bv;
            if (BHEAD) {
                const float* bp = Bm + (size_t)(n >> 6) * (EMB * HDIM)
                                     + (size_t)(k0 + kk) * HDIM + (n & 63);
                bv = *(const float4*)bp;
            } else {
                size_t base = (size_t)(k0 + kk) * N;
                if (((N & 3) == 0) && (n + 3 < N)) {
                    bv = *(const float4*)&Bm[base + n];
                } else {
                    bv.x = (n + 0 < N) ? Bm[base + n + 0] : 0.f;
                    bv.y = (n + 1 < N) ? Bm[base + n + 1] : 0.f;
                    bv.z = (n + 2 < N) ? Bm[base + n + 2] : 0.f;
                    bv.w = (n + 3 < N) ? Bm[base + n + 3] : 0.f;
                }
            }
            *(float4*)&lb[kk][bn] = bv;
        }
        __syncthreads();

#pragma unroll
        for (int kk = 0; kk < BKT; ++kk) {
            float a[8], bb[8];
            *(float4*)&a[0]  = *(const float4*)&la[kk][tm * 8];
            *(float4*)&a[4]  = *(const float4*)&la[kk][tm * 8 + 4];
            *(float4*)&bb[0] = *(const float4*)&lb[kk][tn * 8];
            *(float4*)&bb[4] = *(const float4*)&lb[kk][tn * 8 + 4];
#pragma unroll
            for (int i = 0; i < 8; ++i)
#pragma unroll
                for (int j = 0; j < 8; ++j)
                    acc[i][j] += a[i] * bb[j];
        }
        __syncthreads();
    }

    // epilogue
#pragma unroll
    for (int i = 0; i < 8; ++i) {
        int row = m0 + tm * 8 + i;
        if (CQKV) {
            int t = row & (SEQ - 1), bb2 = row >> 10;
            int col0 = n0 + tn * 8;
            int hh = col0 >> 6, d0 = col0 & 63;
            size_t ob = ((size_t)(bb2 * NH + hh) * SEQ + t) * HDIM + d0;
            float4 o0, o1;
            o0.x = acc[i][0]; o0.y = acc[i][1]; o0.z = acc[i][2]; o0.w = acc[i][3];
            o1.x = acc[i][4]; o1.y = acc[i][5]; o1.z = acc[i][6]; o1.w = acc[i][7];
            *(float4*)&C[ob] = o0;
            *(float4*)&C[ob + 4] = o1;
        } else {
            size_t rb = (size_t)row * N;
#pragma unroll
            for (int jq = 0; jq < 2; ++jq) {
                int col = n0 + tn * 8 + jq * 4;
                if (((N & 3) == 0) && (col + 3 < N)) {
                    float4 val;
                    float* vv = &val.x;
#pragma unroll
                    for (int j = 0; j < 4; ++j) {
                        float t = acc[i][jq * 4 + j];
                        if (BIAS) t += bias[col + j];
                        if (RES)  t += res[rb + col + j];
                        if (RELU) t = fmaxf(t, 0.f);
                        vv[j] = t;
                    }
                    *(float4*)&C[rb + col] = val;
                } else {
#pragma unroll
                    for (int j = 0; j < 4; ++j) {
                        int c = col + j;
                        if (c < N) {
                            float t = acc[i][jq * 4 + j];
                            if (BIAS) t += bias[c];
                            if (RES)  t += res[rb + c];
                            if (RELU) t = fmaxf(t, 0.f);
                            C[rb + c] = t;
                        }
                    }
                }
            }
        }
    }
}

// ---------------- flash attention (fp32, causal) ----------------
// grid: (B*H, T/64). block 256. q,k,v layout: [b,h,t,d]. o layout: [b,t,e].
__global__ __launch_bounds__(256) void attn_kernel(
    const float* __restrict__ q, const float* __restrict__ k,
    const float* __restrict__ v, float* __restrict__ o)
{
    __shared__ float qs[64 * 68];   // q^T: [d][i]
    __shared__ float ks[64 * 68];   // k^T: [d][j]
    __shared__ float vs[64 * 68];   // v:   [j][d]
    __shared__ float ss[64 * 68];   // S^T/P^T: [j][i]
    __shared__ float alpha_s[64], l_s[64];

    int tid = threadIdx.x;
    int bh = blockIdx.x;
    int t0 = blockIdx.y * 64;
    size_t hb = (size_t)bh * SEQ * HDIM;

    int li  = tid >> 2;            // 0..63
    int ld4 = (tid & 3) << 4;      // 0,16,32,48

    // load Q^T
#pragma unroll
    for (int it = 0; it < 4; ++it) {
        int d = ld4 + it * 4;
        float4 qv = *(const float4*)&q[hb + (size_t)(t0 + li) * HDIM + d];
        qs[(d + 0) * 68 + li] = qv.x; qs[(d + 1) * 68 + li] = qv.y;
        qs[(d + 2) * 68 + li] = qv.z; qs[(d + 3) * 68 + li] = qv.w;
    }

    int tr = tid >> 4, tc = tid & 15;
    float oacc[4][4];
#pragma unroll
    for (int i = 0; i < 4; ++i)
#pragma unroll
        for (int j = 0; j < 4; ++j) oacc[i][j] = 0.f;
    float m_r = -1e30f, l_r = 0.f;   // valid for tid<64

    for (int s0 = 0; s0 <= t0; s0 += 64) {
        __syncthreads();   // prev PV done (and Q visible on first iter via next barrier)
        // load K^T and V
#pragma unroll
        for (int it = 0; it < 4; ++it) {
            int d = ld4 + it * 4;
            float4 kv = *(const float4*)&k[hb + (size_t)(s0 + li) * HDIM + d];
            ks[(d + 0) * 68 + li] = kv.x; ks[(d + 1) * 68 + li] = kv.y;
            ks[(d + 2) * 68 + li] = kv.z; ks[(d + 3) * 68 + li] = kv.w;
            float4 vv = *(const float4*)&v[hb + (size_t)(s0 + li) * HDIM + d];
            *(float4*)&vs[li * 68 + d] = vv;
        }
        __syncthreads();

        // S = Q K^T (4x4 per thread)
        float sacc[4][4];
#pragma unroll
        for (int i = 0; i < 4; ++i)
#pragma unroll
            for (int j = 0; j < 4; ++j) sacc[i][j] = 0.f;
#pragma unroll 16
        for (int d = 0; d < 64; ++d) {
            float4 aq = *(const float4*)&qs[d * 68 + tr * 4];
            float4 bk = *(const float4*)&ks[d * 68 + tc * 4];
            const float av[4] = {aq.x, aq.y, aq.z, aq.w};
            const float bv[4] = {bk.x, bk.y, bk.z, bk.w};
#pragma unroll
            for (int i = 0; i < 4; ++i)
#pragma unroll
                for (int j = 0; j < 4; ++j) sacc[i][j] += av[i] * bv[j];
        }
        // mask + scale, store S^T
#pragma unroll
        for (int i = 0; i < 4; ++i) {
            int t = t0 + tr * 4 + i;
#pragma unroll
            for (int j = 0; j < 4; ++j) {
                int sg = s0 + tc * 4 + j;
                float val = (sg <= t) ? sacc[i][j] * ATT_SCALE : -1e30f;
                ss[(tc * 4 + j) * 68 + tr * 4 + i] = val;
            }
        }
        __syncthreads();

        // online softmax per row (one wave)
        if (tid < 64) {
            int r = tid;
            float mx = m_r;
#pragma unroll 8
            for (int j = 0; j < 64; ++j) mx = fmaxf(mx, ss[j * 68 + r]);
            float al = __expf(m_r - mx);
            float sum = 0.f;
#pragma unroll 8
            for (int j = 0; j < 64; ++j) {
                float p = __expf(ss[j * 68 + r] - mx);
                ss[j * 68 + r] = p;
                sum += p;
            }
            l_r = al * l_r + sum;
            m_r = mx;
            alpha_s[r] = al;
        }
        __syncthreads();

        // rescale O, accumulate P @ V
#pragma unroll
        for (int i = 0; i < 4; ++i) {
            float a = alpha_s[tr * 4 + i];
#pragma unroll
            for (int j = 0; j < 4; ++j) oacc[i][j] *= a;
        }
#pragma unroll 16
        for (int j = 0; j < 64; ++j) {
            float4 ap = *(const float4*)&ss[j * 68 + tr * 4];
            float4 bv = *(const float4*)&vs[j * 68 + tc * 4];
            const float av[4] = {ap.x, ap.y, ap.z, ap.w};
            const float vv[4] = {bv.x, bv.y, bv.z, bv.w};
#pragma unroll
            for (int i = 0; i < 4; ++i)
#pragma unroll
                for (int jj = 0; jj < 4; ++jj) oacc[i][jj] += av[i] * vv[jj];
        }
    }

    if (tid < 64) l_s[tid] = l_r;
    __syncthreads();

    int bb = bh / NH, hh = bh % NH;
#pragma unroll
    for (int i = 0; i < 4; ++i) {
        float inv = 1.f / l_s[tr * 4 + i];
        float4 ov;
        ov.x = oacc[i][0] * inv; ov.y = oacc[i][1] * inv;
        ov.z = oacc[i][2] * inv; ov.w = oacc[i][3] * inv;
        size_t ob = ((size_t)(bb * SEQ + t0 + tr * 4 + i)) * EMB + hh * HDIM + tc * 4;
        *(float4*)&o[ob] = ov;
    }
}

// ---------------- fp32 -> bf16 elementwise convert ----------------
__global__ __launch_bounds__(256) void cvt_bf16_kernel(
    const float* __restrict__ in, ushort_t* __restrict__ out, int n4)
{
    int i = blockIdx.x * 256 + threadIdx.x;
    if (i >= n4) return;
    float4 v = ((const float4*)in)[i];
    ushort4 o = make_ushort4(f2bf(v.x), f2bf(v.y), f2bf(v.z), f2bf(v.w));
    ((ushort4*)out)[i] = o;
}

// ---------------- Wh (K x N fp32) -> whB (N x K bf16) tiled transpose-convert ----------------
__global__ __launch_bounds__(256) void cvt_wh_kernel(
    const float* __restrict__ wh, ushort_t* __restrict__ whB)
{
    __shared__ float t[32][33];
    int n0 = blockIdx.x * 32, k0 = blockIdx.y * 32;
    int tx = threadIdx.x & 31, ty = threadIdx.x >> 5;   // tx 0..31, ty 0..7
#pragma unroll
    for (int r = 0; r < 4; ++r) {
        int kk = ty + r * 8;
        int n = n0 + tx;
        t[tx][kk] = (n < NVOCAB) ? wh[(size_t)(k0 + kk) * NVOCAB + n] : 0.f;
    }
    __syncthreads();
#pragma unroll
    for (int r = 0; r < 4; ++r) {
        int nl = ty + r * 8;
        int n = n0 + nl;
        if (n < NVOCAB) whB[(size_t)n * EMB + k0 + tx] = f2bf(t[nl][tx]);
    }
}

// ---------------- bf16 MFMA GEMM for logits: C = A(M,K) @ Bt(N,K)^T + bias ----------------
// A: bf16 row-major M x K. Bt: bf16 n-major N x K. C: fp32 M x N.
// 128x128 tile, BK=32, 4 waves (2x2), each wave 64x64 = 4x4 frags of 16x16x32 MFMA.
__global__ __launch_bounds__(256) void gemm_bf16_logits(
    const ushort_t* __restrict__ A, const ushort_t* __restrict__ Bt,
    const float* __restrict__ bias, float* __restrict__ C,
    int M, int N, int K)
{
    __shared__ ushort_t aT[128][40];   // [m][k], row padded to 80 B (bank stride 20)
    __shared__ ushort_t bT[128][40];   // [n][k]

    int tid  = threadIdx.x;
    int m0   = blockIdx.x * 128, n0 = blockIdx.y * 128;
    int wave = tid >> 6, lane = tid & 63;
    int wr = wave >> 1, wc = wave & 1;      // wave grid 2x2
    int fm = lane & 15, fk = lane >> 4;     // frag row/col, k-group (k = fk*8 + j)

    float4v acc[4][4];
#pragma unroll
    for (int i = 0; i < 4; ++i)
#pragma unroll
        for (int j = 0; j < 4; ++j) acc[i][j] = (float4v){0.f, 0.f, 0.f, 0.f};

    int srow = tid >> 2;              // 0..63 (+64 on 2nd pass)
    int sc   = (tid & 3) * 8;         // k element offset: 0,8,16,24

    for (int k0 = 0; k0 < K; k0 += 32) {
#pragma unroll
        for (int h = 0; h < 2; ++h) {
            int r = srow + h * 64;
            *(uint4*)&aT[r][sc] = *(const uint4*)&A[(size_t)(m0 + r) * K + k0 + sc];
            int nrow = n0 + r;
            uint4 bv = {0u, 0u, 0u, 0u};
            if (nrow < N) bv = *(const uint4*)&Bt[(size_t)nrow * K + k0 + sc];
            *(uint4*)&bT[r][sc] = bv;
        }
        __syncthreads();

        short8v af[4], bfv[4];
#pragma unroll
        for (int i = 0; i < 4; ++i)
            af[i] = *(const short8v*)&aT[wr * 64 + i * 16 + fm][fk * 8];
#pragma unroll
        for (int j = 0; j < 4; ++j)
            bfv[j] = *(const short8v*)&bT[wc * 64 + j * 16 + fm][fk * 8];
#pragma unroll
        for (int i = 0; i < 4; ++i)
#pragma unroll
            for (int j = 0; j < 4; ++j)
                acc[i][j] = __builtin_amdgcn_mfma_f32_16x16x32_bf16(
                    af[i], bfv[j], acc[i][j], 0, 0, 0);
        __syncthreads();
    }

    // C/D layout (m89/m91-verified): col = lane&15, row = (lane>>4)*4 + reg
#pragma unroll
    for (int i = 0; i < 4; ++i) {
        int row = m0 + wr * 64 + i * 16 + fk * 4;
#pragma unroll
        for (int j = 0; j < 4; ++j) {
            int col = n0 + wc * 64 + j * 16 + fm;
            if (col < N) {
                float bb = bias[col];
#pragma unroll
                for (int r = 0; r < 4; ++r)
                    C[(size_t)(row + r) * N + col] = acc[i][j][r] + bb;
            }
        }
    }
}

// ---------------- launch ----------------
extern "C" void kernel_launch(void* const* d_in, const int* in_sizes, int n_in,
                              void* d_out, int out_size, void* d_ws, size_t ws_size,
                              hipStream_t stream)
{
    const int*   idx  = (const int*)  d_in[0];
    const float* tok  = (const float*)d_in[1];
    const float* pos  = (const float*)d_in[2];
    const float* Wq   = (const float*)d_in[3];
    const float* Wk   = (const float*)d_in[4];
    const float* Wv   = (const float*)d_in[5];
    const float* Wo   = (const float*)d_in[6];
    const float* bo   = (const float*)d_in[7];
    const float* ln1g = (const float*)d_in[8];
    const float* ln1b = (const float*)d_in[9];
    const float* ln2g = (const float*)d_in[10];
    const float* ln2b = (const float*)d_in[11];
    const float* W1   = (const float*)d_in[12];
    const float* b1   = (const float*)d_in[13];
    const float* W2   = (const float*)d_in[14];
    const float* b2   = (const float*)d_in[15];
    const float* lnfg = (const float*)d_in[16];
    const float* lnfb = (const float*)d_in[17];
    const float* Wh   = (const float*)d_in[18];
    const float* bh   = (const float*)d_in[19];
    float* out = (float*)d_out;

    float* ws = (float*)d_ws;
    const size_t NE = (size_t)NTOK * EMB;      // 3,145,728
    float* x  = ws;
    float* xn = x + NE;        // also reused as attention output 'o'
    float* qb = xn + NE;
    float* kb = qb + NE;
    float* vb = kb + NE;
    float* hb2 = vb + NE;      // 4096 x 3072
    float* ob = xn;            // alias: ln1 output consumed before attn writes

    // bf16 region (after the 9*NE fp32 floats)
    const size_t fp32_bytes = (size_t)9 * NE * 4;                       // 113,246,208
    const size_t whB_bytes  = (size_t)NVOCAB * EMB * 2;                 //  77,194,752
    const size_t xnB_bytes  = NE * 2;                                   //   6,291,456
    const bool use_bf16 = (ws_size >= fp32_bytes + whB_bytes + xnB_bytes);
    ushort_t* whB = (ushort_t*)((char*)d_ws + fp32_bytes);
    ushort_t* xnB = (ushort_t*)((char*)d_ws + fp32_bytes + whB_bytes);

    embed_kernel<<<dim3((NTOK * (EMB / 4) + 255) / 256), 256, 0, stream>>>(idx, tok, pos, x);

    for (int l = 0; l < NLAYER; ++l) {
        const float* wq = Wq + (size_t)l * NH * EMB * HDIM;
        const float* wk = Wk + (size_t)l * NH * EMB * HDIM;
        const float* wv = Wv + (size_t)l * NH * EMB * HDIM;
        const float* wo = Wo + (size_t)l * EMB * EMB;

        ln_kernel<<<NTOK, 256, 0, stream>>>(x, ln1g + l * EMB, ln1b + l * EMB, xn);

        dim3 gqkv(NTOK / 128, EMB / 128);
        gemm_kernel<true, true, false, false, false><<<gqkv, 256, 0, stream>>>(
            xn, wq, nullptr, nullptr, qb, NTOK, EMB, EMB);
        gemm_kernel<true, true, false, false, false><<<gqkv, 256, 0, stream>>>(
            xn, wk, nullptr, nullptr, kb, NTOK, EMB, EMB);
        gemm_kernel<true, true, false, false, false><<<gqkv, 256, 0, stream>>>(
            xn, wv, nullptr, nullptr, vb, NTOK, EMB, EMB);

        attn_kernel<<<dim3(4 * NH, SEQ / 64), 256, 0, stream>>>(qb, kb, vb, ob);

        gemm_kernel<false, false, true, true, false><<<dim3(NTOK / 128, EMB / 128), 256, 0, stream>>>(
            ob, wo, bo + l * EMB, x, x, NTOK, EMB, EMB);

        ln_kernel<<<NTOK, 256, 0, stream>>>(x, ln2g + l * EMB, ln2b + l * EMB, xn);

        gemm_kernel<false, false, true, false, true><<<dim3(NTOK / 128, (4 * EMB) / 128), 256, 0, stream>>>(
            xn, W1 + (size_t)l * EMB * 4 * EMB, b1 + (size_t)l * 4 * EMB, nullptr, hb2,
            NTOK, 4 * EMB, EMB);

        gemm_kernel<false, false, true, true, false><<<dim3(NTOK / 128, EMB / 128), 256, 0, stream>>>(
            hb2, W2 + (size_t)l * 4 * EMB * EMB, b2 + l * EMB, x, x, NTOK, EMB, 4 * EMB);
    }

    ln_kernel<<<NTOK, 256, 0, stream>>>(x, lnfg, lnfb, xn);

    if (use_bf16) {
        cvt_wh_kernel<<<dim3((NVOCAB + 31) / 32, EMB / 32), 256, 0, stream>>>(Wh, whB);
        cvt_bf16_kernel<<<dim3((int)(NE / 4 / 256)), 256, 0, stream>>>(xn, xnB, (int)(NE / 4));
        gemm_bf16_logits<<<dim3(NTOK / 128, (NVOCAB + 127) / 128), 256, 0, stream>>>(
            xnB, whB, bh, out, NTOK, NVOCAB, EMB);
    } else {
        gemm_kernel<false, false, true, false, false><<<dim3(NTOK / 128, (NVOCAB + 127) / 128), 256, 0, stream>>>(
            xn, Wh, bh, nullptr, out, NTOK, NVOCAB, EMB);
    }
}